// Round 5
// baseline (135.540 us; speedup 1.0000x reference)
//
#include <hip/hip_runtime.h>
#include <stdint.h>

#define H 240
#define W 320
#define NPIX (H * W)          // 76800
#define NCLS 10
#define COLS 4                // columns per vote block
#define BIN_BITS 20
#define BIN_MASK 0xFFFFFu

// d_ws layout (bytes):
//   [0,40)    uint32 cls_count[10]   (= cmask.sum per class)
//   [64,144)  u64    best[10]        (atomicMax key: (count<<20)|(MASK-bin))
//   [192,232) uint32 icnt[10]
//   [256,296) float  dsum[10]
//   [512,...) uint2  list[10][NPIX]  ({x|y<<16, slope bits})

__global__ void k_init(uint32_t* ws) {
    int i = threadIdx.x;
    if (i < 128) ws[i] = 0;   // zero first 512 bytes (all counters/keys)
}

// Hierarchical-aggregated compaction: LDS per-class counters -> one global
// atomicAdd per class per block (3K total vs 70K contended in R1).
__global__ __launch_bounds__(256) void k_compact(const int* __restrict__ label,
                                                 const float* __restrict__ cm,
                                                 uint32_t* __restrict__ cls_cnt,
                                                 uint2* __restrict__ list) {
    __shared__ uint32_t lcnt[NCLS];
    __shared__ uint32_t lbase[NCLS];
    int p = blockIdx.x * 256 + threadIdx.x;   // NPIX % 256 == 0, no OOB
    if (threadIdx.x < NCLS) lcnt[threadIdx.x] = 0;
    __syncthreads();

    int l = label[p];
    bool match = (l >= 1 && l <= NCLS);
    int cls = l - 1;
    uint32_t li = 0;
    if (match) li = atomicAdd(&lcnt[cls], 1u);
    __syncthreads();

    if (threadIdx.x < NCLS) {
        uint32_t c = lcnt[threadIdx.x];
        lbase[threadIdx.x] = c ? atomicAdd(&cls_cnt[threadIdx.x], c) : 0u;
    }
    __syncthreads();

    if (match) {
        float dirx = cm[(cls * 3 + 0) * NPIX + p];
        float diry = cm[(cls * 3 + 1) * NPIX + p];
        float slope = diry / dirx;
        int y = p / W, x = p - y * W;
        uint2 e;
        e.x = (uint32_t)(x | (y << 16));
        e.y = __float_as_uint(slope);
        list[cls * NPIX + lbase[cls] + li] = e;
    }
}

__global__ __launch_bounds__(256) void k_vote(const uint32_t* __restrict__ cls_cnt,
                                              const uint2* __restrict__ list,
                                              unsigned long long* __restrict__ best) {
    int cls = blockIdx.y;
    int x0 = blockIdx.x * COLS;
    __shared__ uint32_t hist[COLS][H];
    __shared__ unsigned long long wred[4];
    for (int i = threadIdx.x; i < COLS * H; i += 256) ((uint32_t*)hist)[i] = 0;
    __syncthreads();

    int n = (int)cls_cnt[cls];
    const uint2* lst = list + cls * NPIX;
    // Wave-uniform iteration: padding lanes run with valid=false so ballots
    // are well-defined across the full wave.
    for (int i0 = 0; i0 < n; i0 += 256) {
        int i = i0 + (int)threadIdx.x;
        bool inb = (i < n);
        uint2 e;
        e.x = 0u; e.y = 0u;
        if (inb) e = lst[i];
        float slope = __uint_as_float(e.y);
        float xf = (float)(e.x & 0xFFFFu);
        float yf = (float)(e.x >> 16);
#pragma unroll
        for (int c = 0; c < COLS; ++c) {
            float dx = (float)(x0 + c) - xf;
            float r = rintf(yf + slope * dx);   // half-to-even == jnp.round
            // float-domain bounds check: NaN/inf/huge all fail, matching the
            // reference's (y_idx>=0)&(y_idx<H).
            bool valid = inb && (r >= 0.0f) && (r <= (float)(H - 1));
            int bin = (int)r;
            // Intra-wave same-bin aggregation: the hot column (x ~= cx) has
            // nearly all lanes voting the same bin -> 1 atomic, not 64
            // serialized same-address LDS atomics.
            unsigned long long rem = __ballot(valid);
#pragma unroll
            for (int t3 = 0; t3 < 3; ++t3) {
                if (rem == 0ull) break;                    // uniform
                int src = __ffsll((unsigned long long)rem) - 1;
                int b0 = __shfl(bin, src);
                unsigned long long m = __ballot(valid && (bin == b0));
                if ((int)(threadIdx.x & 63u) == src)
                    atomicAdd(&hist[c][b0], (uint32_t)__popcll(m));
                if (valid && (bin == b0)) valid = false;
                rem &= ~m;
            }
            if (valid) atomicAdd(&hist[c][bin], 1u);       // stragglers
        }
    }
    __syncthreads();

    // per-thread scan of the COLS*H bins -> key = (count<<20)|(MASK-bin)
    unsigned long long k = 0;
    for (int i = threadIdx.x; i < COLS * H; i += 256) {
        int c = i / H, y = i - c * H;
        uint32_t v = hist[c][y];
        uint32_t bin = (uint32_t)(y * W + x0 + c);
        unsigned long long key =
            ((unsigned long long)v << BIN_BITS) | (unsigned long long)(BIN_MASK - bin);
        if (key > k) k = key;
    }
    // wave shuffle max, then cross-wave via LDS
#pragma unroll
    for (int off = 32; off > 0; off >>= 1) {
        unsigned long long o = __shfl_down(k, off);
        if (o > k) k = o;
    }
    if ((threadIdx.x & 63u) == 0u) wred[threadIdx.x >> 6] = k;
    __syncthreads();
    if (threadIdx.x == 0) {
        unsigned long long kk = wred[0];
#pragma unroll
        for (int w = 1; w < 4; ++w) if (wred[w] > kk) kk = wred[w];
        atomicMax(&best[cls], kk);
    }
}

__global__ __launch_bounds__(256) void k_inlier(const int* __restrict__ label,
                                                const float* __restrict__ cm,
                                                const unsigned long long* __restrict__ best,
                                                uint32_t* __restrict__ icnt,
                                                float* __restrict__ dsum) {
    int cls = blockIdx.y;
    unsigned long long key = best[cls];
    uint32_t bin = BIN_MASK - (uint32_t)(key & BIN_MASK);
    float cx = (float)(bin % W);
    float cy = (float)(bin / W);

    const float* c0p = cm + (cls * 3 + 0) * NPIX;
    const float* c1p = cm + (cls * 3 + 1) * NPIX;
    const float* c2p = cm + (cls * 3 + 2) * NPIX;

    uint32_t lcnt = 0;
    float ldsum = 0.0f;
    int base = blockIdx.x * 2560;   // 30 blocks * 2560 = 76800
    for (int i = 0; i < 10; ++i) {
        int p = base + i * 256 + threadIdx.x;
        if (label[p] == cls + 1) {
            int y = p / W, x = p - y * W;
            float disx = (float)x - cx;
            float disy = (float)y - cy;
            float dn = sqrtf(disx * disx + disy * disy);
            if (dn > 0.0f) {
                float dot = fabsf((disx / dn) * c0p[p] + (disy / dn) * c1p[p]);
                if (dot >= 0.9f) {
                    lcnt += 1;
                    ldsum += c2p[p];
                }
            }
        }
    }
    // wave reduce, then cross-wave via LDS
#pragma unroll
    for (int off = 32; off > 0; off >>= 1) {
        ldsum += __shfl_down(ldsum, off);
        lcnt += __shfl_down(lcnt, off);
    }
    __shared__ float sd[4];
    __shared__ uint32_t sc[4];
    if ((threadIdx.x & 63u) == 0u) {
        sd[threadIdx.x >> 6] = ldsum;
        sc[threadIdx.x >> 6] = lcnt;
    }
    __syncthreads();
    if (threadIdx.x == 0) {
        float td = sd[0] + sd[1] + sd[2] + sd[3];
        uint32_t tc = sc[0] + sc[1] + sc[2] + sc[3];
        if (tc) atomicAdd(&icnt[cls], tc);
        if (td != 0.0f) atomicAdd(&dsum[cls], td);
    }
}

__global__ void k_final(const uint32_t* __restrict__ cls_cnt,
                        const unsigned long long* __restrict__ best,
                        const uint32_t* __restrict__ icnt,
                        const float* __restrict__ dsum,
                        float* __restrict__ out) {
    int cls = threadIdx.x;
    if (cls >= NCLS) return;
    unsigned long long key = best[cls];
    uint32_t hv = (uint32_t)(key >> BIN_BITS);
    uint32_t bin = BIN_MASK - (uint32_t)(key & BIN_MASK);
    float cx = (float)(bin % W);
    float cy = (float)(bin / W);
    bool trig = (cls_cnt[cls] >= 500u) && (hv > 500u);
    float c = (float)icnt[cls];
    float dm = (c > 0.0f) ? (dsum[cls] / fmaxf(c, 1.0f)) : __builtin_nanf("");
    out[cls * 2 + 0] = trig ? cx : 0.0f;
    out[cls * 2 + 1] = trig ? cy : 0.0f;
    out[2 * NCLS + cls] = trig ? dm : 0.0f;
}

extern "C" void kernel_launch(void* const* d_in, const int* in_sizes, int n_in,
                              void* d_out, int out_size, void* d_ws, size_t ws_size,
                              hipStream_t stream) {
    const int* label = (const int*)d_in[0];
    const float* cm = (const float*)d_in[1];
    float* out = (float*)d_out;
    char* ws = (char*)d_ws;

    uint32_t* cls_cnt = (uint32_t*)(ws + 0);
    unsigned long long* best = (unsigned long long*)(ws + 64);
    uint32_t* icnt = (uint32_t*)(ws + 192);
    float* dsum = (float*)(ws + 256);
    uint2* list = (uint2*)(ws + 512);

    k_init<<<1, 128, 0, stream>>>((uint32_t*)ws);
    k_compact<<<NPIX / 256, 256, 0, stream>>>(label, cm, cls_cnt, list);
    k_vote<<<dim3(W / COLS, NCLS), 256, 0, stream>>>(cls_cnt, list, best);
    k_inlier<<<dim3(30, NCLS), 256, 0, stream>>>(label, cm, best, icnt, dsum);
    k_final<<<1, 64, 0, stream>>>(cls_cnt, best, icnt, dsum, out);
}

// Round 6
// 114.510 us; speedup vs baseline: 1.1837x; 1.1837x over previous
//
#include <hip/hip_runtime.h>
#include <stdint.h>

#define H 240
#define W 320
#define NPIX (H * W)          // 76800
#define NCLS 10
#define COLS 4                // columns per vote block
#define BIN_BITS 20
#define BIN_MASK 0xFFFFFu

// d_ws layout (bytes):
//   [0,40)    uint32 cls_count[10]   (= cmask.sum per class)
//   [64,144)  u64    best[10]        (atomicMax key: (count<<20)|(MASK-bin))
//   [192,232) uint32 icnt[10]
//   [256,296) float  dsum[10]
//   [512,...) uint2  list[10][NPIX]  ({x|y<<16, slope bits})

__global__ void k_init(uint32_t* ws) {
    int i = threadIdx.x;
    if (i < 128) ws[i] = 0;   // zero first 512 bytes (all counters/keys)
}

// Hierarchical-aggregated compaction: LDS per-class counters -> one global
// atomicAdd per class per block (3K total vs 70K contended in R1).
__global__ __launch_bounds__(256) void k_compact(const int* __restrict__ label,
                                                 const float* __restrict__ cm,
                                                 uint32_t* __restrict__ cls_cnt,
                                                 uint2* __restrict__ list) {
    __shared__ uint32_t lcnt[NCLS];
    __shared__ uint32_t lbase[NCLS];
    int p = blockIdx.x * 256 + threadIdx.x;   // NPIX % 256 == 0, no OOB
    if (threadIdx.x < NCLS) lcnt[threadIdx.x] = 0;
    __syncthreads();

    int l = label[p];
    bool match = (l >= 1 && l <= NCLS);
    int cls = l - 1;
    uint32_t li = 0;
    if (match) li = atomicAdd(&lcnt[cls], 1u);
    __syncthreads();

    if (threadIdx.x < NCLS) {
        uint32_t c = lcnt[threadIdx.x];
        lbase[threadIdx.x] = c ? atomicAdd(&cls_cnt[threadIdx.x], c) : 0u;
    }
    __syncthreads();

    if (match) {
        float dirx = cm[(cls * 3 + 0) * NPIX + p];
        float diry = cm[(cls * 3 + 1) * NPIX + p];
        float slope = diry / dirx;
        int y = p / W, x = p - y * W;
        uint2 e;
        e.x = (uint32_t)(x | (y << 16));
        e.y = __float_as_uint(slope);
        list[cls * NPIX + lbase[cls] + li] = e;
    }
}

__global__ __launch_bounds__(256) void k_vote(const uint32_t* __restrict__ cls_cnt,
                                              const uint2* __restrict__ list,
                                              unsigned long long* __restrict__ best) {
    int cls = blockIdx.y;
    int x0 = blockIdx.x * COLS;
    __shared__ uint32_t hist[COLS][H];
    __shared__ unsigned long long wred[4];
    for (int i = threadIdx.x; i < COLS * H; i += 256) ((uint32_t*)hist)[i] = 0;
    __syncthreads();

    int n = (int)cls_cnt[cls];
    const uint2* lst = list + cls * NPIX;
    // Wave-uniform iteration: padding lanes run with valid=false so ballots
    // are well-defined across the full wave.
    for (int i0 = 0; i0 < n; i0 += 256) {
        int i = i0 + (int)threadIdx.x;
        bool inb = (i < n);
        uint2 e;
        e.x = 0u; e.y = 0u;
        if (inb) e = lst[i];
        float slope = __uint_as_float(e.y);
        float xf = (float)(e.x & 0xFFFFu);
        float yf = (float)(e.x >> 16);
#pragma unroll
        for (int c = 0; c < COLS; ++c) {
            float dx = (float)(x0 + c) - xf;
            float r = rintf(yf + slope * dx);   // half-to-even == jnp.round
            // float-domain bounds check: NaN/inf/huge all fail, matching the
            // reference's (y_idx>=0)&(y_idx<H).
            bool valid = inb && (r >= 0.0f) && (r <= (float)(H - 1));
            int bin = (int)r;
            // Single uniform-bin fast path: in the hot column (x ~= cx) ALL
            // valid lanes vote the same bin (every direction points at the
            // center) -> one atomic with popcount payload. Cold columns take
            // plain per-lane atomics spread over ~240 bins (~2-way bank
            // aliasing, free per m136). No multi-round aggregation: R5 showed
            // cold blocks paying 3 useless cross-lane rounds (52.9 us).
            unsigned long long vm = __ballot(valid);
            if (vm != 0ull) {
                int src = __ffsll((unsigned long long)vm) - 1;
                int b0 = __shfl(bin, src);
                unsigned long long sm = __ballot(!valid || bin == b0);
                if (sm == ~0ull) {
                    if ((int)(threadIdx.x & 63u) == src)
                        atomicAdd(&hist[c][b0], (uint32_t)__popcll(vm));
                } else if (valid) {
                    atomicAdd(&hist[c][bin], 1u);
                }
            }
        }
    }
    __syncthreads();

    // per-thread scan of the COLS*H bins -> key = (count<<20)|(MASK-bin)
    unsigned long long k = 0;
    for (int i = threadIdx.x; i < COLS * H; i += 256) {
        int c = i / H, y = i - c * H;
        uint32_t v = hist[c][y];
        uint32_t bin = (uint32_t)(y * W + x0 + c);
        unsigned long long key =
            ((unsigned long long)v << BIN_BITS) | (unsigned long long)(BIN_MASK - bin);
        if (key > k) k = key;
    }
    // wave shuffle max, then cross-wave via LDS
#pragma unroll
    for (int off = 32; off > 0; off >>= 1) {
        unsigned long long o = __shfl_down(k, off);
        if (o > k) k = o;
    }
    if ((threadIdx.x & 63u) == 0u) wred[threadIdx.x >> 6] = k;
    __syncthreads();
    if (threadIdx.x == 0) {
        unsigned long long kk = wred[0];
#pragma unroll
        for (int w = 1; w < 4; ++w) if (wred[w] > kk) kk = wred[w];
        atomicMax(&best[cls], kk);
    }
}

__global__ __launch_bounds__(256) void k_inlier(const int* __restrict__ label,
                                                const float* __restrict__ cm,
                                                const unsigned long long* __restrict__ best,
                                                uint32_t* __restrict__ icnt,
                                                float* __restrict__ dsum) {
    int cls = blockIdx.y;
    unsigned long long key = best[cls];
    uint32_t bin = BIN_MASK - (uint32_t)(key & BIN_MASK);
    float cx = (float)(bin % W);
    float cy = (float)(bin / W);

    const float* c0p = cm + (cls * 3 + 0) * NPIX;
    const float* c1p = cm + (cls * 3 + 1) * NPIX;
    const float* c2p = cm + (cls * 3 + 2) * NPIX;

    uint32_t lcnt = 0;
    float ldsum = 0.0f;
    int base = blockIdx.x * 2560;   // 30 blocks * 2560 = 76800
    for (int i = 0; i < 10; ++i) {
        int p = base + i * 256 + threadIdx.x;
        if (label[p] == cls + 1) {
            int y = p / W, x = p - y * W;
            float disx = (float)x - cx;
            float disy = (float)y - cy;
            float dn = sqrtf(disx * disx + disy * disy);
            if (dn > 0.0f) {
                float dot = fabsf((disx / dn) * c0p[p] + (disy / dn) * c1p[p]);
                if (dot >= 0.9f) {
                    lcnt += 1;
                    ldsum += c2p[p];
                }
            }
        }
    }
    // wave reduce, then cross-wave via LDS
#pragma unroll
    for (int off = 32; off > 0; off >>= 1) {
        ldsum += __shfl_down(ldsum, off);
        lcnt += __shfl_down(lcnt, off);
    }
    __shared__ float sd[4];
    __shared__ uint32_t sc[4];
    if ((threadIdx.x & 63u) == 0u) {
        sd[threadIdx.x >> 6] = ldsum;
        sc[threadIdx.x >> 6] = lcnt;
    }
    __syncthreads();
    if (threadIdx.x == 0) {
        float td = sd[0] + sd[1] + sd[2] + sd[3];
        uint32_t tc = sc[0] + sc[1] + sc[2] + sc[3];
        if (tc) atomicAdd(&icnt[cls], tc);
        if (td != 0.0f) atomicAdd(&dsum[cls], td);
    }
}

__global__ void k_final(const uint32_t* __restrict__ cls_cnt,
                        const unsigned long long* __restrict__ best,
                        const uint32_t* __restrict__ icnt,
                        const float* __restrict__ dsum,
                        float* __restrict__ out) {
    int cls = threadIdx.x;
    if (cls >= NCLS) return;
    unsigned long long key = best[cls];
    uint32_t hv = (uint32_t)(key >> BIN_BITS);
    uint32_t bin = BIN_MASK - (uint32_t)(key & BIN_MASK);
    float cx = (float)(bin % W);
    float cy = (float)(bin / W);
    bool trig = (cls_cnt[cls] >= 500u) && (hv > 500u);
    float c = (float)icnt[cls];
    float dm = (c > 0.0f) ? (dsum[cls] / fmaxf(c, 1.0f)) : __builtin_nanf("");
    out[cls * 2 + 0] = trig ? cx : 0.0f;
    out[cls * 2 + 1] = trig ? cy : 0.0f;
    out[2 * NCLS + cls] = trig ? dm : 0.0f;
}

extern "C" void kernel_launch(void* const* d_in, const int* in_sizes, int n_in,
                              void* d_out, int out_size, void* d_ws, size_t ws_size,
                              hipStream_t stream) {
    const int* label = (const int*)d_in[0];
    const float* cm = (const float*)d_in[1];
    float* out = (float*)d_out;
    char* ws = (char*)d_ws;

    uint32_t* cls_cnt = (uint32_t*)(ws + 0);
    unsigned long long* best = (unsigned long long*)(ws + 64);
    uint32_t* icnt = (uint32_t*)(ws + 192);
    float* dsum = (float*)(ws + 256);
    uint2* list = (uint2*)(ws + 512);

    k_init<<<1, 128, 0, stream>>>((uint32_t*)ws);
    k_compact<<<NPIX / 256, 256, 0, stream>>>(label, cm, cls_cnt, list);
    k_vote<<<dim3(W / COLS, NCLS), 256, 0, stream>>>(cls_cnt, list, best);
    k_inlier<<<dim3(30, NCLS), 256, 0, stream>>>(label, cm, best, icnt, dsum);
    k_final<<<1, 64, 0, stream>>>(cls_cnt, best, icnt, dsum, out);
}

// Round 7
// 107.899 us; speedup vs baseline: 1.2562x; 1.0613x over previous
//
#include <hip/hip_runtime.h>
#include <stdint.h>

#define H 240
#define W 320
#define NPIX (H * W)          // 76800
#define NCLS 10
#define COLS 4                // columns per vote block
#define BIN_BITS 20
#define BIN_MASK 0xFFFFFu

// d_ws layout (bytes):
//   [0,40)    uint32 cls_count[10]   (= cmask.sum per class)
//   [64,144)  u64    best[10]        (atomicMax key: (count<<20)|(MASK-bin))
//   [192,232) uint32 icnt[10]
//   [256,296) float  dsum[10]
//   [320,324) uint32 done            (last-block counter for fused finalize)
//   [512,...) uint2  list[10][NPIX]  ({x|y<<16, slope bits})

__global__ void k_init(uint32_t* ws) {
    int i = threadIdx.x;
    if (i < 128) ws[i] = 0;   // zero first 512 bytes (all counters/keys/done)
}

// Hierarchical-aggregated compaction: LDS per-class counters -> one global
// atomicAdd per class per block (3K total vs 70K contended in R1).
__global__ __launch_bounds__(256) void k_compact(const int* __restrict__ label,
                                                 const float* __restrict__ cm,
                                                 uint32_t* __restrict__ cls_cnt,
                                                 uint2* __restrict__ list) {
    __shared__ uint32_t lcnt[NCLS];
    __shared__ uint32_t lbase[NCLS];
    int p = blockIdx.x * 256 + threadIdx.x;   // NPIX % 256 == 0, no OOB
    if (threadIdx.x < NCLS) lcnt[threadIdx.x] = 0;
    __syncthreads();

    int l = label[p];
    bool match = (l >= 1 && l <= NCLS);
    int cls = l - 1;
    uint32_t li = 0;
    if (match) li = atomicAdd(&lcnt[cls], 1u);
    __syncthreads();

    if (threadIdx.x < NCLS) {
        uint32_t c = lcnt[threadIdx.x];
        lbase[threadIdx.x] = c ? atomicAdd(&cls_cnt[threadIdx.x], c) : 0u;
    }
    __syncthreads();

    if (match) {
        float dirx = cm[(cls * 3 + 0) * NPIX + p];
        float diry = cm[(cls * 3 + 1) * NPIX + p];
        float slope = diry / dirx;
        int y = p / W, x = p - y * W;
        uint2 e;
        e.x = (uint32_t)(x | (y << 16));
        e.y = __float_as_uint(slope);
        list[cls * NPIX + lbase[cls] + li] = e;
    }
}

__global__ __launch_bounds__(256) void k_vote(const uint32_t* __restrict__ cls_cnt,
                                              const uint2* __restrict__ list,
                                              unsigned long long* __restrict__ best) {
    int cls = blockIdx.y;
    int x0 = blockIdx.x * COLS;
    __shared__ uint32_t hist[COLS][H];
    __shared__ unsigned long long wred[4];
    for (int i = threadIdx.x; i < COLS * H; i += 256) ((uint32_t*)hist)[i] = 0;
    __syncthreads();

    int n = (int)cls_cnt[cls];
    const uint2* lst = list + cls * NPIX;
    // Wave-uniform iteration: padding lanes run with valid=false so ballots
    // are well-defined across the full wave.
    for (int i0 = 0; i0 < n; i0 += 256) {
        int i = i0 + (int)threadIdx.x;
        bool inb = (i < n);
        uint2 e;
        e.x = 0u; e.y = 0u;
        if (inb) e = lst[i];
        float slope = __uint_as_float(e.y);
        float xf = (float)(e.x & 0xFFFFu);
        float yf = (float)(e.x >> 16);
#pragma unroll
        for (int c = 0; c < COLS; ++c) {
            float dx = (float)(x0 + c) - xf;
            float r = rintf(yf + slope * dx);   // half-to-even == jnp.round
            // float-domain bounds check: NaN/inf/huge all fail, matching the
            // reference's (y_idx>=0)&(y_idx<H).
            bool valid = inb && (r >= 0.0f) && (r <= (float)(H - 1));
            int bin = (int)r;
            // Single uniform-bin fast path: hot column (x ~= cx) -> all valid
            // lanes same bin -> 1 atomic with popcount payload. Cold columns:
            // plain per-lane atomics spread over ~240 bins (cheap per m136).
            unsigned long long vm = __ballot(valid);
            if (vm != 0ull) {
                int src = __ffsll((unsigned long long)vm) - 1;
                int b0 = __shfl(bin, src);
                unsigned long long sm = __ballot(!valid || bin == b0);
                if (sm == ~0ull) {
                    if ((int)(threadIdx.x & 63u) == src)
                        atomicAdd(&hist[c][b0], (uint32_t)__popcll(vm));
                } else if (valid) {
                    atomicAdd(&hist[c][bin], 1u);
                }
            }
        }
    }
    __syncthreads();

    // per-thread scan of the COLS*H bins -> key = (count<<20)|(MASK-bin)
    unsigned long long k = 0;
    for (int i = threadIdx.x; i < COLS * H; i += 256) {
        int c = i / H, y = i - c * H;
        uint32_t v = hist[c][y];
        uint32_t bin = (uint32_t)(y * W + x0 + c);
        unsigned long long key =
            ((unsigned long long)v << BIN_BITS) | (unsigned long long)(BIN_MASK - bin);
        if (key > k) k = key;
    }
    // wave shuffle max, then cross-wave via LDS
#pragma unroll
    for (int off = 32; off > 0; off >>= 1) {
        unsigned long long o = __shfl_down(k, off);
        if (o > k) k = o;
    }
    if ((threadIdx.x & 63u) == 0u) wred[threadIdx.x >> 6] = k;
    __syncthreads();
    if (threadIdx.x == 0) {
        unsigned long long kk = wred[0];
#pragma unroll
        for (int w = 1; w < 4; ++w) if (wred[w] > kk) kk = wred[w];
        atomicMax(&best[cls], kk);
    }
}

// Single-pass inlier over ALL classes (each pixel contributes only to its own
// label's class) + fused finalize via deadlock-free last-block-done pattern.
__global__ __launch_bounds__(256) void k_inlier_final(
    const int* __restrict__ label, const float* __restrict__ cm,
    const uint32_t* __restrict__ cls_cnt,
    const unsigned long long* __restrict__ best,
    uint32_t* __restrict__ icnt, float* __restrict__ dsum,
    uint32_t* __restrict__ done, float* __restrict__ out) {
    __shared__ float scx[NCLS], scy[NCLS];
    __shared__ uint32_t scnt[NCLS];
    __shared__ float ssum[NCLS];
    __shared__ int slast;
    int tid = threadIdx.x;
    if (tid < NCLS) {
        unsigned long long key = best[tid];
        uint32_t bin = BIN_MASK - (uint32_t)(key & BIN_MASK);
        scx[tid] = (float)(bin % W);
        scy[tid] = (float)(bin / W);
        scnt[tid] = 0u;
        ssum[tid] = 0.0f;
    }
    __syncthreads();

    int p = blockIdx.x * 256 + tid;           // 300 blocks * 256 = NPIX
    int l = label[p];
    if (l >= 1 && l <= NCLS) {
        int cls = l - 1;
        int y = p / W, x = p - y * W;
        float disx = (float)x - scx[cls];
        float disy = (float)y - scy[cls];
        float dn = sqrtf(disx * disx + disy * disy);
        if (dn > 0.0f) {                      // dn==0 -> NaN dot in ref -> excluded
            float c0 = cm[(cls * 3 + 0) * NPIX + p];
            float c1 = cm[(cls * 3 + 1) * NPIX + p];
            float dot = fabsf((disx / dn) * c0 + (disy / dn) * c1);
            if (dot >= 0.9f) {
                atomicAdd(&scnt[cls], 1u);
                atomicAdd(&ssum[cls], cm[(cls * 3 + 2) * NPIX + p]);
            }
        }
    }
    __syncthreads();

    if (tid < NCLS) {
        if (scnt[tid]) atomicAdd(&icnt[tid], scnt[tid]);
        if (ssum[tid] != 0.0f) atomicAdd(&dsum[tid], ssum[tid]);
    }
    if (tid == 0) {
        __threadfence();                      // publish our atomics device-wide
        uint32_t d = atomicAdd(done, 1u);
        slast = (d == (uint32_t)(gridDim.x - 1)) ? 1 : 0;
    }
    __syncthreads();

    if (slast && tid < NCLS) {
        // device-coherent totals via atomic fetch-add-0 (bypass stale L1)
        uint32_t tc = atomicAdd(&icnt[tid], 0u);
        float td = atomicAdd(&dsum[tid], 0.0f);
        unsigned long long key = best[tid];
        uint32_t hv = (uint32_t)(key >> BIN_BITS);
        bool trig = (cls_cnt[tid] >= 500u) && (hv > 500u);
        float c = (float)tc;
        float dm = (c > 0.0f) ? (td / fmaxf(c, 1.0f)) : __builtin_nanf("");
        out[tid * 2 + 0] = trig ? scx[tid] : 0.0f;
        out[tid * 2 + 1] = trig ? scy[tid] : 0.0f;
        out[2 * NCLS + tid] = trig ? dm : 0.0f;
    }
}

extern "C" void kernel_launch(void* const* d_in, const int* in_sizes, int n_in,
                              void* d_out, int out_size, void* d_ws, size_t ws_size,
                              hipStream_t stream) {
    const int* label = (const int*)d_in[0];
    const float* cm = (const float*)d_in[1];
    float* out = (float*)d_out;
    char* ws = (char*)d_ws;

    uint32_t* cls_cnt = (uint32_t*)(ws + 0);
    unsigned long long* best = (unsigned long long*)(ws + 64);
    uint32_t* icnt = (uint32_t*)(ws + 192);
    float* dsum = (float*)(ws + 256);
    uint32_t* done = (uint32_t*)(ws + 320);
    uint2* list = (uint2*)(ws + 512);

    k_init<<<1, 128, 0, stream>>>((uint32_t*)ws);
    k_compact<<<NPIX / 256, 256, 0, stream>>>(label, cm, cls_cnt, list);
    k_vote<<<dim3(W / COLS, NCLS), 256, 0, stream>>>(cls_cnt, list, best);
    k_inlier_final<<<NPIX / 256, 256, 0, stream>>>(label, cm, cls_cnt, best,
                                                   icnt, dsum, done, out);
}